// Round 7
// baseline (377.807 us; speedup 1.0000x reference)
//
#include <hip/hip_runtime.h>
#include <hip/hip_fp16.h>

#define NNODES 100000
#define NEDGES 1600000
#define BN_EPS 1e-5f
#define L2_EPS 1e-12f

#define BKT_SHIFT 9
#define BKT_SIZE  512
#define NBKT      196            // ceil(100000/512)
#define CHUNK     8192
#define NBLK_E    196            // ceil(1600000/8192)
#define NSLOT     64             // BN-stats shard count
#define NPB       64             // nodes per layer-block (divides BKT_SIZE)
#define SRCMASK   0x03FFFFFFu    // low 26 bits of packed col = src id

// ---------------------------------------------------------------------------
// Wave-level block exclusive scan (NT threads). Leading barrier protects wsum
// reuse across consecutive calls.
template<int NT>
__device__ __forceinline__ int block_excl_scan(int v, int* wsum) {
    __syncthreads();
    constexpr int NW = NT / 64;
    int incl = v;
#pragma unroll
    for (int off = 1; off < 64; off <<= 1) {
        int t = __shfl_up(incl, off);
        if ((threadIdx.x & 63) >= off) incl += t;
    }
    int wid = threadIdx.x >> 6;
    if ((threadIdx.x & 63) == 63) wsum[wid] = incl;
    __syncthreads();
    if (threadIdx.x < NW) {
        int w = wsum[threadIdx.x];
#pragma unroll
        for (int off = 1; off < NW; off <<= 1) {
            int t = __shfl_up(w, off);
            if ((int)threadIdx.x >= off) w += t;
        }
        wsum[threadIdx.x] = w;             // inclusive wave sums
    }
    __syncthreads();
    int base = wid ? wsum[wid - 1] : 0;
    return base + incl - v;
}

// ---------------------------------------------------------------------------
// Pass 1: per-block bucket histogram (LDS) -> transposed blk_hist. Block 0
// also zeroes the sharded BN stats accumulators.
__global__ void hist_kernel(const int* __restrict__ dst,
                            int* __restrict__ blk_hist_T, float* __restrict__ stats) {
    __shared__ int h[NBKT];
    for (int i = threadIdx.x; i < NBKT; i += blockDim.x) h[i] = 0;
    if (blockIdx.x == 0)
        for (int i = threadIdx.x; i < 3 * NSLOT * 64; i += blockDim.x) stats[i] = 0.0f;
    __syncthreads();
    int base = blockIdx.x * CHUNK;
    int end  = min(base + CHUNK, NEDGES);
    for (int e = base + threadIdx.x * 4; e < end; e += blockDim.x * 4) {
        int4 d = *reinterpret_cast<const int4*>(dst + e);
        atomicAdd(&h[d.x >> BKT_SHIFT], 1);
        atomicAdd(&h[d.y >> BKT_SHIFT], 1);
        atomicAdd(&h[d.z >> BKT_SHIFT], 1);
        atomicAdd(&h[d.w >> BKT_SHIFT], 1);
    }
    __syncthreads();
    for (int i = threadIdx.x; i < NBKT; i += blockDim.x)
        blk_hist_T[i * NBLK_E + blockIdx.x] = h[i];   // [bucket][block]
}

// Per-bucket exclusive scan across blocks + bucket totals as by-product.
__global__ void scan_blocks(const int* __restrict__ blk_hist_T,
                            int* __restrict__ blk_off, int* __restrict__ bucket_total) {
    __shared__ int wsum[4];
    int b = blockIdx.x;
    int i = threadIdx.x;
    int v = (i < NBLK_E) ? blk_hist_T[b * NBLK_E + i] : 0;
    int excl = block_excl_scan<256>(v, wsum);
    if (i < NBLK_E) blk_off[i * NBKT + b] = excl;     // [block][bucket]
    if (i == 255) bucket_total[b] = excl + v;
}

// Pass 2: scatter edges into bucket segments (packed dst_local<<23 | src).
__global__ void bucket_scatter(const int* __restrict__ src, const int* __restrict__ dst,
                               const int* __restrict__ blk_off, const int* __restrict__ bucket_total,
                               unsigned int* __restrict__ staged) {
    __shared__ int cur[NBKT];
    __shared__ int wsum[8];
    int v = (threadIdx.x < NBKT) ? bucket_total[threadIdx.x] : 0;
    int bbase = block_excl_scan<512>(v, wsum);
    if (threadIdx.x < NBKT)
        cur[threadIdx.x] = bbase + blk_off[blockIdx.x * NBKT + threadIdx.x];
    __syncthreads();
    int base = blockIdx.x * CHUNK;
    int end  = min(base + CHUNK, NEDGES);
    for (int e = base + threadIdx.x * 4; e < end; e += blockDim.x * 4) {
        int4 d = *reinterpret_cast<const int4*>(dst + e);
        int4 s = *reinterpret_cast<const int4*>(src + e);
        int p0 = atomicAdd(&cur[d.x >> BKT_SHIFT], 1);
        staged[p0] = ((unsigned)(d.x & (BKT_SIZE - 1)) << 23) | (unsigned)s.x;
        int p1 = atomicAdd(&cur[d.y >> BKT_SHIFT], 1);
        staged[p1] = ((unsigned)(d.y & (BKT_SIZE - 1)) << 23) | (unsigned)s.y;
        int p2 = atomicAdd(&cur[d.z >> BKT_SHIFT], 1);
        staged[p2] = ((unsigned)(d.z & (BKT_SIZE - 1)) << 23) | (unsigned)s.z;
        int p3 = atomicAdd(&cur[d.w >> BKT_SHIFT], 1);
        staged[p3] = ((unsigned)(d.w & (BKT_SIZE - 1)) << 23) | (unsigned)s.w;
    }
}

// Pass 3: one block per bucket -> exact CSR. col entries carry the node-local
// id (within a 64-node layer block) in the top 6 bits: (l & 63) << 26 | src.
__global__ void csr_finalize(const unsigned int* __restrict__ staged,
                             const int* __restrict__ bucket_total,
                             int* __restrict__ row_ptr, unsigned int* __restrict__ col) {
    __shared__ int nh[BKT_SIZE];
    __shared__ int cur[BKT_SIZE];
    __shared__ int wsum[8];
    __shared__ int sBeg, sEnd;
    int b = blockIdx.x;

    nh[threadIdx.x] = 0;                      // covered by scan's leading barrier
    int v = (threadIdx.x < NBKT) ? bucket_total[threadIdx.x] : 0;
    int excl = block_excl_scan<512>(v, wsum);
    if (threadIdx.x == b) { sBeg = excl; sEnd = excl + v; }
    __syncthreads();
    int beg = sBeg, end = sEnd;

    for (int e = beg + threadIdx.x; e < end; e += blockDim.x)
        atomicAdd(&nh[staged[e] >> 23], 1);
    __syncthreads();

    int hv = nh[threadIdx.x];
    int hexcl = block_excl_scan<512>(hv, wsum);

    int node = b * BKT_SIZE + threadIdx.x;
    if (node < NNODES) row_ptr[node] = beg + hexcl;
    if (b == 0 && threadIdx.x == 0) row_ptr[NNODES] = NEDGES;
    cur[threadIdx.x] = hexcl;
    __syncthreads();

    for (int e = beg + threadIdx.x; e < end; e += blockDim.x) {
        unsigned pk = staged[e];
        int l = (int)(pk >> 23);
        int p = atomicAdd(&cur[l], 1);          // LDS atomic only
        col[beg + p] = ((unsigned)(l & (NPB - 1)) << 26) | (pk & 0x7FFFFF);
    }
}

// ---------------------------------------------------------------------------
__device__ __forceinline__ void unpack8(uint4 v, float* f) {
    float2 a = __half22float2(*(const __half2*)&v.x);
    float2 b = __half22float2(*(const __half2*)&v.y);
    float2 c = __half22float2(*(const __half2*)&v.z);
    float2 d = __half22float2(*(const __half2*)&v.w);
    f[0] = a.x; f[1] = a.y; f[2] = b.x; f[3] = b.y;
    f[4] = c.x; f[5] = c.y; f[6] = d.x; f[7] = d.y;
}

// ---------------------------------------------------------------------------
// Two-phase fused layer, blocked-run edge assignment + batch-4 pipeline.
// Round-7 change: intermediate h tables are FP16 (L2-resident per XCD ->
// the ~73MB L2-miss stream that bounded rounds 2-6 collapses to compulsory).
// Phase A: thread = (contiguous edge run, 16B channel chunk). Lanes executing
//   together sit in DIFFERENT runs (no LDS-atomic same-address serialization);
//   register accumulate, flush-on-dst-change; rows for batch b+1 / cols for
//   batch b+2 prefetched. Accumulation is FP32 in LDS.
// Phase B: node-parallel linear + L2 norm + ReLU + BN stats (all FP32).
template<int CI, int CIL, int SI, int CO, int SO,
         bool IN_HALF, bool OUT_HALF, bool IN_AFFINE, bool DO_STATS>
__global__ __launch_bounds__(512, 4)
void layer_kernel(const int* __restrict__ row_ptr, const unsigned int* __restrict__ col,
                  const void* __restrict__ hvoid,
                  const float* __restrict__ ssum_in, const float* __restrict__ ssq_in,
                  const float* __restrict__ g_in, const float* __restrict__ b_in,
                  const float* __restrict__ wl, const float* __restrict__ bl,
                  const float* __restrict__ wr,
                  void* __restrict__ yvoid,
                  float* __restrict__ stat_sum, float* __restrict__ stat_sq) {
    constexpr int W    = IN_HALF ? 8 : 4;    // channels per 16B chunk
    constexpr int CIp  = CI + 1;             // padded weight stride
    constexpr int CILp = CIL + 1;            // padded acc stride (odd -> bank spread)
    constexpr int NCH  = CIL / W;            // chunks per edge
    constexpr int NRUN = 512 / NCH;          // contiguous runs per block
    constexpr int TPN  = 512 / NPB;          // 8 threads per node
    constexpr int OPT  = (CO + TPN - 1) / TPN;

    __shared__ float acc[NPB * CILp];
    __shared__ float sWl[CO * CIp];
    __shared__ float sWr[CO * CIp];
    __shared__ float sBl[CO];
    __shared__ float sSc[CI];
    __shared__ float sSh[CI];
    __shared__ int   sRP[NPB + 1];
    __shared__ float sSumR[CI];
    __shared__ float sSqR[CI];
    __shared__ float red_sum[CO];
    __shared__ float red_sq[CO];

    const float*  hf = (const float*)hvoid;
    const __half* hh = (const __half*)hvoid;

    int tid = threadIdx.x;
    for (int i = tid; i < CO * CI; i += 512) {
        int o = i / CI, c = i - o * CI;
        sWl[o * CIp + c] = wl[i];
        sWr[o * CIp + c] = wr[i];
    }
    if (tid < CO) {
        sBl[tid] = bl[tid];
        if (DO_STATS) { red_sum[tid] = 0.0f; red_sq[tid] = 0.0f; }
    }
    for (int i = tid; i < NPB * CILp; i += 512) acc[i] = 0.0f;
    int first = blockIdx.x * NPB;
    if (tid <= NPB) sRP[tid] = row_ptr[min(first + tid, NNODES)];
    if (IN_AFFINE && tid < CI) { sSumR[tid] = 0.0f; sSqR[tid] = 0.0f; }
    __syncthreads();
    if (IN_AFFINE) {
        int c = tid & 31, sl = tid >> 5;     // 16 slices over NSLOT shards
        if (c < CI) {
            float ps = 0.0f, pq = 0.0f;
#pragma unroll
            for (int s = sl; s < NSLOT; s += 16) {
                ps += ssum_in[s * 64 + c];
                pq += ssq_in[s * 64 + c];
            }
            atomicAdd(&sSumR[c], ps);
            atomicAdd(&sSqR[c], pq);
        }
        __syncthreads();
        if (tid < CI) {
            float m  = sSumR[tid] * (1.0f / NNODES);
            float vv = sSqR[tid] * (1.0f / NNODES) - m * m;
            float s  = g_in[tid] / sqrtf(vv + BN_EPS);
            sSc[tid] = s;
            sSh[tid] = b_in[tid] - m * s;
        }
        __syncthreads();
    }

    // ---- Phase A: blocked-run, batch-4 pipelined accumulate ----
    {
        int ebeg = sRP[0], eend = sRP[NPB];
        int M = eend - ebeg;
        int L = (M + NRUN - 1) / NRUN;       // run length
        int run = tid / NCH;
        int chw = (tid & (NCH - 1)) * W;     // my channel offset
        int s  = ebeg + run * L;
        int se = min(s + L, eend);

        float racc[W];
#pragma unroll
        for (int q = 0; q < W; q++) racc[q] = 0.0f;
        int cur_d = -1;

        auto rowld = [&](unsigned c) -> uint4 {
            long idx = (long)(c & SRCMASK) * SI + chw;
            if constexpr (IN_HALF) return *(const uint4*)(hh + idx);
            else                   return *(const uint4*)(hf + idx);
        };
        auto flush = [&]() {
            if (cur_d >= 0) {
                int a_ = cur_d * CILp + chw;
#pragma unroll
                for (int q = 0; q < W; q++) atomicAdd(&acc[a_ + q], racc[q]);
            }
        };
        auto accum = [&](unsigned cc, uint4 rv) {
            float f[W];
            if constexpr (IN_HALF) {
                unpack8(rv, f);
            } else {
                float4 t = *(const float4*)&rv;
                f[0] = t.x; f[1] = t.y; f[2] = t.z; f[3] = t.w;
            }
            int d_ = (int)(cc >> 26);
            if (d_ != cur_d) {
                flush();
                cur_d = d_;
#pragma unroll
                for (int q = 0; q < W; q++) racc[q] = f[q];
            } else {
#pragma unroll
                for (int q = 0; q < W; q++) racc[q] += f[q];
            }
        };

        unsigned cA[4], cB[4];
        uint4 rA[4];
#pragma unroll
        for (int i = 0; i < 4; i++) cA[i] = (s + i < se) ? col[s + i] : 0u;
#pragma unroll
        for (int i = 0; i < 4; i++)
            rA[i] = (s + i < se) ? rowld(cA[i]) : make_uint4(0, 0, 0, 0);
#pragma unroll
        for (int i = 0; i < 4; i++) cB[i] = (s + 4 + i < se) ? col[s + 4 + i] : 0u;

        for (int b = s; b < se; b += 4) {
            uint4 rB[4];
#pragma unroll
            for (int i = 0; i < 4; i++)
                rB[i] = (b + 4 + i < se) ? rowld(cB[i]) : make_uint4(0, 0, 0, 0);
            unsigned cC[4];
#pragma unroll
            for (int i = 0; i < 4; i++) cC[i] = (b + 8 + i < se) ? col[b + 8 + i] : 0u;
#pragma unroll
            for (int i = 0; i < 4; i++) if (b + i < se) accum(cA[i], rA[i]);
#pragma unroll
            for (int i = 0; i < 4; i++) { cA[i] = cB[i]; cB[i] = cC[i]; rA[i] = rB[i]; }
        }
        flush();
    }
    __syncthreads();

    // ---- Phase B: node-parallel epilogue (8 threads per node) ----
    int nl = tid / TPN, t = tid & (TPN - 1);
    int node = first + nl;
    bool valid = node < NNODES;

    float outv[OPT];
    float nrm2 = 0.0f;
    if (valid) {
        int deg = sRP[nl + 1] - sRP[nl];
        float ic = 1.0f / fmaxf((float)deg, 1.0f);
        float xin[CI];
        if constexpr (IN_HALF) {
            constexpr int NU = (CI + 7) / 8;
            float tmp[NU * 8];
#pragma unroll
            for (int u = 0; u < NU; u++) {
                uint4 v = *(const uint4*)(hh + (long)node * SI + u * 8);
                unpack8(v, &tmp[u * 8]);
            }
#pragma unroll
            for (int c = 0; c < CI; c++) xin[c] = tmp[c];
        } else {
#pragma unroll
            for (int c = 0; c < CI; c += 4) {
                float4 v = *(const float4*)(hf + (long)node * SI + c);
                xin[c] = v.x; xin[c + 1] = v.y; xin[c + 2] = v.z; xin[c + 3] = v.w;
            }
        }
        float a[CI];
#pragma unroll
        for (int c = 0; c < CI; c++) {
            float av = acc[nl * CILp + c] * ic;
            float xv = xin[c];
            if (IN_AFFINE) {
                av = av * sSc[c] + sSh[c];
                xv = xv * sSc[c] + sSh[c];
            }
            a[c] = av;
            xin[c] = xv;
        }
#pragma unroll
        for (int k = 0; k < OPT; k++) {
            int o = t * OPT + k;
            float v = 0.0f;
            if (o < CO) {
                v = sBl[o];
#pragma unroll
                for (int c = 0; c < CI; c++)
                    v += sWl[o * CIp + c] * a[c] + sWr[o * CIp + c] * xin[c];
            }
            outv[k] = v;
            nrm2 += v * v;
        }
    }
    nrm2 += __shfl_xor(nrm2, 1);             // 8-lane group = one node
    nrm2 += __shfl_xor(nrm2, 2);
    nrm2 += __shfl_xor(nrm2, 4);

    if (valid) {
        float inv_nrm = 1.0f / fmaxf(sqrtf(nrm2), L2_EPS);
#pragma unroll
        for (int k = 0; k < OPT; k++) {
            int o = t * OPT + k;
            float v = (o < CO) ? fmaxf(outv[k] * inv_nrm, 0.0f) : 0.0f;
            if constexpr (OUT_HALF) {
                __half* yh = (__half*)yvoid;
                if (o < SO) yh[(long)node * SO + o] = __float2half_rn(v);  // pad ch -> 0
            } else {
                float* yf = (float*)yvoid;
                if (o < CO) yf[(long)node * SO + o] = v;
            }
            if (DO_STATS && o < CO) {
                atomicAdd(&red_sum[o], v);
                atomicAdd(&red_sq[o], v * v);
            }
        }
    }

    if (DO_STATS) {
        __syncthreads();
        if (tid < CO) {
            int slot = blockIdx.x & (NSLOT - 1);
            atomicAdd(&stat_sum[slot * 64 + tid], red_sum[tid]);
            atomicAdd(&stat_sq [slot * 64 + tid], red_sq[tid]);
        }
    }
}

// ---------------------------------------------------------------------------
extern "C" void kernel_launch(void* const* d_in, const int* in_sizes, int n_in,
                              void* d_out, int out_size, void* d_ws, size_t ws_size,
                              hipStream_t stream) {
    const float* x   = (const float*)d_in[0];
    const int*   ei  = (const int*)d_in[1];
    const int*   src = ei;
    const int*   dst = ei + NEDGES;

    const float* w1l = (const float*)d_in[2];
    const float* b1l = (const float*)d_in[3];
    const float* w1r = (const float*)d_in[4];
    const float* w2l = (const float*)d_in[5];
    const float* b2l = (const float*)d_in[6];
    const float* w2r = (const float*)d_in[7];
    const float* w3l = (const float*)d_in[8];
    const float* b3l = (const float*)d_in[9];
    const float* w3r = (const float*)d_in[10];
    const float* w4l = (const float*)d_in[11];
    const float* b4l = (const float*)d_in[12];
    const float* w4r = (const float*)d_in[13];
    const float* g1  = (const float*)d_in[14];
    const float* be1 = (const float*)d_in[15];
    const float* g2  = (const float*)d_in[16];
    const float* be2 = (const float*)d_in[17];
    const float* g3  = (const float*)d_in[18];
    const float* be3 = (const float*)d_in[19];

    char* w = (char*)d_ws;
    int* blk_hist     = (int*)w;  w += NBLK_E * NBKT * 4;
    int* blk_off      = (int*)w;  w += NBLK_E * NBKT * 4;
    int* bucket_total = (int*)w;  w += 256 * 4;
    int* row_ptr      = (int*)w;  w += (NNODES + 8) * 4;
    unsigned int* col = (unsigned int*)w; w += NEDGES * 4;
    __half* hA        = (__half*)w; w += NNODES * 16 * 4;  // fp16 tables (over-alloc)
    __half* hB        = (__half*)w; w += NNODES * 16 * 4;  // aliased by staged
    float* stats      = (float*)w; w += 3 * NSLOT * 64 * 4;
    unsigned int* staged = (unsigned int*)hB;  // dead before hB is written

    float* ssum1 = stats + 0 * NSLOT * 64, *ssq1 = ssum1 + 32;
    float* ssum2 = stats + 1 * NSLOT * 64, *ssq2 = ssum2 + 32;
    float* ssum3 = stats + 2 * NSLOT * 64, *ssq3 = ssum3 + 32;

    // atomic-free CSR build (LDS atomics only), 4 launches
    hist_kernel   <<<NBLK_E, 512, 0, stream>>>(dst, blk_hist, stats);
    scan_blocks   <<<NBKT, 256, 0, stream>>>(blk_hist, blk_off, bucket_total);
    bucket_scatter<<<NBLK_E, 512, 0, stream>>>(src, dst, blk_off, bucket_total, staged);
    csr_finalize  <<<NBKT, 512, 0, stream>>>(staged, bucket_total, row_ptr, col);

    const int NLBLK = (NNODES + NPB - 1) / NPB;   // 1563

    // layer 1: 4 -> 6; in fp32 x (SI=4), out fp16 hA (SO=8 halves), +stats
    layer_kernel<4, 4, 4, 6, 8, false, true, false, true><<<NLBLK, 512, 0, stream>>>(
        row_ptr, col, x, nullptr, nullptr, nullptr, nullptr,
        w1l, b1l, w1r, hA, ssum1, ssq1);

    // layer 2: 6 -> 8; in fp16 hA (CIL=8, SI=8), out fp16 hB, BN1 in-block, +stats
    layer_kernel<6, 8, 8, 8, 8, true, true, true, true><<<NLBLK, 512, 0, stream>>>(
        row_ptr, col, hA, ssum1, ssq1, g1, be1,
        w2l, b2l, w2r, hB, ssum2, ssq2);

    // layer 3: 8 -> 16; in fp16 hB (SI=8), out fp16 hA (SO=16 halves), +stats
    layer_kernel<8, 8, 8, 16, 16, true, true, true, true><<<NLBLK, 512, 0, stream>>>(
        row_ptr, col, hB, ssum2, ssq2, g2, be2,
        w3l, b3l, w3r, hA, ssum3, ssq3);

    // layer 4: 16 -> 32; in fp16 hA (CIL=16, SI=16), out fp32 d_out
    layer_kernel<16, 16, 16, 32, 32, true, false, true, false><<<NLBLK, 512, 0, stream>>>(
        row_ptr, col, hA, ssum3, ssq3, g3, be3,
        w4l, b4l, w4r, d_out, nullptr, nullptr);
}